// Round 8
// baseline (434.512 us; speedup 1.0000x reference)
//
#include <hip/hip_runtime.h>

typedef __bf16 bf16;
typedef __bf16 bf16x4 __attribute__((ext_vector_type(4)));
typedef __bf16 bf16x8 __attribute__((ext_vector_type(8)));
typedef float f32x4 __attribute__((ext_vector_type(4)));

#define N_ROWS 65536

// ---- packed (PRE-SWIZZLED, k-slice-contiguous) weight layout in d_ws ----
// Each k-slice is contiguous: for row r, word w(0..31): value = W[r][s*32 + ((w>>3)^swz4(r))*8 + (w&7)]
// W1 : 24 slices x 13312 B (208 rows)   | W12: 7 x 7168 B (112 rows)
// W13:  4 slices x  7168 B (112 rows)   | W2 : 4g x 4 x 8192 B (128 rows)
#define W1_E   159744
#define W12_E  25088
#define W13_E  14336
#define W2_E   65536
#define WP_TOTAL (W1_E + W12_E + W13_E + W2_E)        // 264704 elems
#define W12_OFF_B 319488
#define W13_OFF_B 369664
#define W2_OFF_B  398336
#define BP_OFF_BYTES (WP_TOTAL * 2)                   // 529408
#define BP_FLOATS 944
#define ACC_OFF_BYTES (BP_OFF_BYTES + BP_FLOATS * 4)  // 533184 (16B aligned)
#define NCOPY 16
#define P0_IDX (NCOPY * 256)                          // 4096
#define S_IDX0 (P0_IDX + 1)                           // 4097..4112
#define P3_IDX0 (S_IDX0 + NCOPY)                      // 4113..4128
#define ACC_FLOATS (P3_IDX0 + NCOPY)                  // 4129

__device__ inline int swz4(int r) { return (r ^ (r >> 2)) & 3; }

__global__ void pack_kernel(const float* __restrict__ W1, const float* __restrict__ b1,
                            const float* __restrict__ W12, const float* __restrict__ b12,
                            const float* __restrict__ W13, const float* __restrict__ b13,
                            const float* __restrict__ W2, const float* __restrict__ b2,
                            bf16* __restrict__ wp, float* __restrict__ bp) {
  int i = blockIdx.x * 256 + threadIdx.x;
  if (i < WP_TOTAL) {
    float v = 0.0f;
    if (i < W1_E) {
      int s = i / 6656, b = i - s * 6656;
      int r = b >> 5, w = b & 31;
      int k = s * 32 + (((w >> 3) ^ swz4(r)) << 3) + (w & 7);
      if (r < 200) v = W1[r * 768 + k];
    } else if (i < W1_E + W12_E) {
      int j = i - W1_E;
      int s = j / 3584, b = j - s * 3584;
      int r = b >> 5, w = b & 31;
      int k = s * 32 + (((w >> 3) ^ swz4(r)) << 3) + (w & 7);
      if (r < 100 && k < 200) v = W12[r * 200 + k];
    } else if (i < W1_E + W12_E + W13_E) {
      int j = i - (W1_E + W12_E);
      int s = j / 3584, b = j - s * 3584;
      int r = b >> 5, w = b & 31;
      int k = s * 32 + (((w >> 3) ^ swz4(r)) << 3) + (w & 7);
      if (r < 100 && k < 100) v = W13[r * 100 + k];
    } else {
      int j = i - (W1_E + W12_E + W13_E);
      int g = j >> 14, rest = j & 16383;
      int s = rest >> 12, b = rest & 4095;
      int r = b >> 5, w = b & 31;
      int o = g * 128 + r;
      int k = s * 32 + (((w >> 3) ^ swz4(r)) << 3) + (w & 7);
      if (k < 100) v = W2[o * 100 + k];
    }
    wp[i] = (bf16)v;
  } else {
    int j = i - WP_TOTAL;
    if (j < BP_FLOATS) {
      float v = 0.0f;
      if (j < 208)      { if (j < 200) v = b1[j]; }
      else if (j < 320) { int o = j - 208; if (o < 100) v = b12[o]; }
      else if (j < 432) { int o = j - 320; if (o < 100) v = b13[o]; }
      else              { v = b2[j - 432]; }
      bp[j] = v;
    }
  }
}

#define MFMA(a, b, c) __builtin_amdgcn_mfma_f32_16x16x32_bf16((a), (b), (c), 0, 0, 0)

__device__ inline bf16x8 cvt8(const float* __restrict__ p) {
  f32x4 lo = *(const f32x4*)p;
  f32x4 hi = *(const f32x4*)(p + 4);
  bf16x8 r;
#pragma unroll
  for (int i = 0; i < 4; i++) { r[i] = (bf16)lo[i]; r[4 + i] = (bf16)hi[i]; }
  return r;
}

// Direct global->LDS staging of one pre-swizzled weight k-slice.
template<int BYTES>
__device__ inline void stage(const char* __restrict__ src, bf16* __restrict__ dstw, int tid) {
  char* dst = (char*)dstw;
  const int off0 = (tid >> 6) * 1024 + (tid & 63) * 16;
  constexpr int NCH = (BYTES + 4095) / 4096;
#pragma unroll
  for (int j = 0; j < NCH; j++) {
    const int off = j * 4096 + off0;
    if ((BYTES & 4095) == 0 || off < BYTES)
      __builtin_amdgcn_global_load_lds(
          (const __attribute__((address_space(1))) void*)(src + off),
          (__attribute__((address_space(3))) void*)(dst + off),
          16, 0, 0);
  }
}

// Block = 256 threads = 4 waves, TWO 16-row tiles per wave (A at m0, B at
// m0+64; block covers 128 rows). Layer-1 k-loop keeps both accumulator sets
// and shares every staged weight slice AND every B-fragment ds_read between
// the tiles: per-CU LDS-DMA bytes (the hypothesized limiter) halve in L1.
// L2/L3/L4 run per-tile afterwards (accB parked in registers during A's
// tail). h statistics fused as in round 7 (batched register loads, shfl
// pairing); A-frags are direct global cvt8 loads (A-panel LDS dropped).
__global__ __launch_bounds__(256, 2) void mlp_main(
    const float* __restrict__ input, const float* __restrict__ h,
    const bf16* __restrict__ wp, const float* __restrict__ bp,
    float* __restrict__ out, float* __restrict__ acc) {
  __shared__ __align__(16) bf16 acts[4][3712];   // x1 16x232 | x2/x3 16x136 | hred overlay
  __shared__ __align__(16) bf16 wbuf[2][6656];   // 2 x 13312 B weight slices
  __shared__ float wred[4][3];                   // per-wave {p0, S, P3} partials

  const int tid = threadIdx.x;
  const int lane = tid & 63;
  const int wave = tid >> 6;
  const int c16 = lane & 15;
  const int quad = lane >> 4;
  const int m0A = blockIdx.x * 128 + wave * 16;
  const int m0B = m0A + 64;
  const int qs8 = (quad ^ swz4(c16)) * 8;

  const char* wpb = (const char*)wp;
  const float* b1p  = bp;
  const float* b12p = bp + 208;
  const float* b13p = bp + 320;
  const float* b2p  = bp + 432;

  bf16* actw = &acts[wave][0];

  // fused h-stat accumulators (both tiles accumulate into the same regs)
  f32x4 csA = (f32x4){0.f, 0.f, 0.f, 0.f};   // colsum partial, cols 0..127
  f32x4 csB = (f32x4){0.f, 0.f, 0.f, 0.f};   // colsum partial, cols 128..255
  float s2loc = 0.0f, p3loc = 0.0f;
  float p0local = 0.0f;

  // batched h loads for stats: lane covers rows 2i+(lane>>5), cols (lane&31)*4
  f32x4 ar[8];
  auto loadH = [&](int base, int half) {
#pragma unroll
    for (int i = 0; i < 8; i++) {
      const int row = 2 * i + (lane >> 5);
      ar[i] = *(const f32x4*)(h + (size_t)(base + row) * 256 + half * 128 + (lane & 31) * 4);
    }
  };
  auto statsH = [&](f32x4* cs) {
#pragma unroll
    for (int i = 0; i < 8; i++) {
      f32x4 oth;
#pragma unroll
      for (int c = 0; c < 4; c++) oth[c] = __shfl_xor(ar[i][c], 32);
      *cs += ar[i];
#pragma unroll
      for (int c = 0; c < 4; c++) s2loc += ar[i][c] * ar[i][c];
      if (lane < 32) {            // pair (2i, 2i+1)
#pragma unroll
        for (int c = 0; c < 4; c++) p3loc += __builtin_fabsf(oth[c] - ar[i][c]);
      } else if (i >= 1) {        // pair (2i-1, 2i)
#pragma unroll
        for (int c = 0; c < 4; c++) p3loc += __builtin_fabsf(oth[c] - ar[i - 1][c]);
      }
    }
  };

  // ---------------- Layer 1 (SHARED staging): (2x 16x768) @ W1^T ----------------
  f32x4 accA[13], accB[13];
#pragma unroll
  for (int t = 0; t < 13; t++) {
    accA[t] = (f32x4){0.f, 0.f, 0.f, 0.f};
    accB[t] = (f32x4){0.f, 0.f, 0.f, 0.f};
  }

  stage<13312>(wpb, wbuf[0], tid);
  __syncthreads();

  const float* aArow = input + (size_t)(m0A + c16) * 512 + quad * 8;
  const float* aBrow = input + (size_t)(m0B + c16) * 512 + quad * 8;
  const float* hArow = h + (size_t)(m0A + c16) * 256 + quad * 8;
  const float* hBrow = h + (size_t)(m0B + c16) * 256 + quad * 8;

  for (int ks = 0; ks < 24; ks++) {
    if (ks + 1 < 24) stage<13312>(wpb + (ks + 1) * 13312, wbuf[(ks + 1) & 1], tid);
    // stats machinery spread across steps (loads one step ahead of use)
    if (ks == 15) loadH(m0A, 0);
    else if (ks == 16) statsH(&csA);
    else if (ks == 17) loadH(m0A, 1);
    else if (ks == 18) statsH(&csB);
    else if (ks == 19) loadH(m0B, 0);
    else if (ks == 20) statsH(&csA);
    else if (ks == 21) loadH(m0B, 1);
    else if (ks == 22) statsH(&csB);
    const int k0 = ks * 32;
    bf16x8 aA = (k0 < 512) ? cvt8(aArow + k0) : cvt8(hArow + (k0 - 512));
    bf16x8 aB = (k0 < 512) ? cvt8(aBrow + k0) : cvt8(hBrow + (k0 - 512));
    const bf16* buf = wbuf[ks & 1];
#pragma unroll
    for (int t = 0; t < 13; t++) {
      bf16x8 bb = *(const bf16x8*)(buf + (t * 16 + c16) * 32 + qs8);  // read ONCE, used twice
      accA[t] = MFMA(aA, bb, accA[t]);
      accB[t] = MFMA(aB, bb, accB[t]);
    }
    __syncthreads();
  }

  // ---------------- per-tile L2/L3/L4 ----------------
  auto runL234 = [&](f32x4 (&acc1)[13], int m0) {
    // x1 = relu(acc1 + b1) -> actw (wave-private; no barrier needed)
#pragma unroll
    for (int t = 0; t < 13; t++) {
      const float bias = b1p[t * 16 + c16];
#pragma unroll
      for (int r = 0; r < 4; r++)
        actw[(quad * 4 + r) * 232 + t * 16 + c16] = (bf16)fmaxf(acc1[t][r] + bias, 0.0f);
    }
    for (int idx = lane; idx < 256; idx += 64)
      actw[(idx >> 4) * 232 + 208 + (idx & 15)] = (bf16)0.0f;

    // Layer 2: (16x224) @ W12^T -> 16x112
    f32x4 acc2[7];
#pragma unroll
    for (int t = 0; t < 7; t++) acc2[t] = (f32x4){0.f, 0.f, 0.f, 0.f};
    stage<7168>(wpb + W12_OFF_B, wbuf[0], tid);
    __syncthreads();
#pragma unroll
    for (int ks = 0; ks < 7; ks++) {
      if (ks + 1 < 7) stage<7168>(wpb + W12_OFF_B + (ks + 1) * 7168, wbuf[(ks + 1) & 1], tid);
      bf16x8 a = *(const bf16x8*)(actw + c16 * 232 + ks * 32 + quad * 8);
      const bf16* buf = wbuf[ks & 1];
#pragma unroll
      for (int t = 0; t < 7; t++) {
        bf16x8 bb = *(const bf16x8*)(buf + (t * 16 + c16) * 32 + qs8);
        acc2[t] = MFMA(a, bb, acc2[t]);
      }
      __syncthreads();
    }
#pragma unroll
    for (int t = 0; t < 7; t++) {
      const float bias = b12p[t * 16 + c16];
#pragma unroll
      for (int r = 0; r < 4; r++)
        actw[(quad * 4 + r) * 136 + t * 16 + c16] = (bf16)fmaxf(acc2[t][r] + bias, 0.0f);
    }
    for (int idx = lane; idx < 256; idx += 64)
      actw[(idx >> 4) * 136 + 112 + (idx & 15)] = (bf16)0.0f;

    // Layer 3: (16x128) @ W13^T -> 16x112
    f32x4 acc3[7];
#pragma unroll
    for (int t = 0; t < 7; t++) acc3[t] = (f32x4){0.f, 0.f, 0.f, 0.f};
    stage<7168>(wpb + W13_OFF_B, wbuf[0], tid);
    __syncthreads();
#pragma unroll
    for (int ks = 0; ks < 4; ks++) {
      if (ks + 1 < 4) stage<7168>(wpb + W13_OFF_B + (ks + 1) * 7168, wbuf[(ks + 1) & 1], tid);
      bf16x8 a = *(const bf16x8*)(actw + c16 * 136 + ks * 32 + quad * 8);
      const bf16* buf = wbuf[ks & 1];
#pragma unroll
      for (int t = 0; t < 7; t++) {
        bf16x8 bb = *(const bf16x8*)(buf + (t * 16 + c16) * 32 + qs8);
        acc3[t] = MFMA(a, bb, acc3[t]);
      }
      __syncthreads();
    }
#pragma unroll
    for (int t = 0; t < 7; t++) {
      const float bias = b13p[t * 16 + c16];
#pragma unroll
      for (int r = 0; r < 4; r++)
        actw[(quad * 4 + r) * 136 + t * 16 + c16] = (bf16)fmaxf(acc3[t][r] + bias, 0.0f);
    }
    for (int idx = lane; idx < 256; idx += 64)
      actw[(idx >> 4) * 136 + 112 + (idx & 15)] = (bf16)0.0f;

    // Layer 4: (16x128) @ W2^T -> 16x512 (+ part0)
    for (int g = 0; g < 4; g++) {
      f32x4 acc4[8];
#pragma unroll
      for (int t = 0; t < 8; t++) acc4[t] = (f32x4){0.f, 0.f, 0.f, 0.f};
      const char* Wg = wpb + W2_OFF_B + g * 32768;
      stage<8192>(Wg, wbuf[0], tid);
      __syncthreads();
#pragma unroll
      for (int ks = 0; ks < 4; ks++) {
        if (ks + 1 < 4) stage<8192>(Wg + (ks + 1) * 8192, wbuf[(ks + 1) & 1], tid);
        bf16x8 a = *(const bf16x8*)(actw + c16 * 136 + ks * 32 + quad * 8);
        const bf16* buf = wbuf[ks & 1];
#pragma unroll
        for (int t = 0; t < 8; t++) {
          bf16x8 bb = *(const bf16x8*)(buf + (t * 16 + c16) * 32 + qs8);
          acc4[t] = MFMA(a, bb, acc4[t]);
        }
        __syncthreads();
      }
#pragma unroll
      for (int t = 0; t < 8; t++) {
        const int o = g * 128 + t * 16 + c16;
        const float bias = b2p[o];
#pragma unroll
        for (int r = 0; r < 4; r++) {
          const int grow = m0 + quad * 4 + r;
          float v = acc4[t][r] + bias;
          out[(size_t)grow * 512 + o] = v;
          if (grow < N_ROWS - 1) {
            float d = v - input[(size_t)(grow + 1) * 512 + o];
            p0local += d * d;
          }
        }
      }
    }
  };

  runL234(accA, m0A);
  runL234(accB, m0B);

  // ---------------- fused-reduction epilogue ----------------
  // boundary pairs (row % 16 == 15): 8 per block (128 rows); group g = tid>>5
  // (32 threads) handles pair (row, row+1), each thread 8 cols. L2-hot.
  {
    const int g = tid >> 5, cq = tid & 31;
    const int rowA = blockIdx.x * 128 + g * 16 + 15;
    if (rowA + 1 < N_ROWS) {
      f32x4 a0 = *(const f32x4*)(h + (size_t)rowA * 256 + cq * 8);
      f32x4 a1 = *(const f32x4*)(h + (size_t)rowA * 256 + cq * 8 + 4);
      f32x4 b0 = *(const f32x4*)(h + (size_t)(rowA + 1) * 256 + cq * 8);
      f32x4 b1 = *(const f32x4*)(h + (size_t)(rowA + 1) * 256 + cq * 8 + 4);
#pragma unroll
      for (int c = 0; c < 4; c++) {
        p3loc += __builtin_fabsf(b0[c] - a0[c]);
        p3loc += __builtin_fabsf(b1[c] - a1[c]);
      }
    }
  }
  // combine lane-halves of the colsum partials
#pragma unroll
  for (int c = 0; c < 4; c++) {
    csA[c] += __shfl_xor(csA[c], 32);
    csB[c] += __shfl_xor(csB[c], 32);
  }
  // block colsum reduce via LDS aliased onto dead acts region
  f32x4* hred = (f32x4*)&acts[0][0];   // 4 waves x 64 col-quads x 16B = 4 KB
  __syncthreads();                      // all acts reads done before overlay
  if (lane < 32) hred[wave * 64 + lane] = csA;
  else           hred[wave * 64 + 32 + (lane & 31)] = csB;
#pragma unroll
  for (int off = 32; off > 0; off >>= 1) {
    p0local += __shfl_down(p0local, off);
    s2loc   += __shfl_down(s2loc, off);
    p3loc   += __shfl_down(p3loc, off);
  }
  if (lane == 0) { wred[wave][0] = p0local; wred[wave][1] = s2loc; wred[wave][2] = p3loc; }
  __syncthreads();
  if (tid < 64) {
    f32x4 tot = hred[tid] + hred[64 + tid] + hred[128 + tid] + hred[192 + tid];
    float* dst = acc + (blockIdx.x & (NCOPY - 1)) * 256 + tid * 4;
    atomicAdd(dst + 0, tot[0]);
    atomicAdd(dst + 1, tot[1]);
    atomicAdd(dst + 2, tot[2]);
    atomicAdd(dst + 3, tot[3]);
  }
  if (tid == 0) {
    atomicAdd(&acc[P0_IDX], wred[0][0] + wred[1][0] + wred[2][0] + wred[3][0]);
    atomicAdd(&acc[S_IDX0 + (blockIdx.x & (NCOPY - 1))], wred[0][1] + wred[1][1] + wred[2][1] + wred[3][1]);
    atomicAdd(&acc[P3_IDX0 + (blockIdx.x & (NCOPY - 1))], wred[0][2] + wred[1][2] + wred[2][2] + wred[3][2]);
  }
}

__global__ void finalize(const float* __restrict__ acc, float* __restrict__ out) {
  __shared__ float red[256];
  const int t = threadIdx.x;
  float s = 0.0f;
#pragma unroll
  for (int j = 0; j < NCOPY; j++) s += acc[j * 256 + t];
  red[t] = fabsf(s);
  __syncthreads();
  for (int st = 128; st > 0; st >>= 1) {
    if (t < st) red[t] += red[t + st];
    __syncthreads();
  }
  if (t == 0) {
    float Ssum = 0.f, Psum = 0.f;
#pragma unroll
    for (int j = 0; j < NCOPY; j++) { Ssum += acc[S_IDX0 + j]; Psum += acc[P3_IDX0 + j]; }
    out[(size_t)N_ROWS * 512 + 0] = sqrtf(acc[P0_IDX]) / 65535.0f;
    out[(size_t)N_ROWS * 512 + 1] = red[0] / 65536.0f / 256.0f;
    out[(size_t)N_ROWS * 512 + 2] = fabsf(Ssum / (65536.0f * 256.0f) - 1.0f);
    out[(size_t)N_ROWS * 512 + 3] = Psum / (65535.0f * 256.0f);
  }
}

extern "C" void kernel_launch(void* const* d_in, const int* in_sizes, int n_in,
                              void* d_out, int out_size, void* d_ws, size_t ws_size,
                              hipStream_t stream) {
  const float* input = (const float*)d_in[0];
  const float* h   = (const float*)d_in[1];
  const float* W1  = (const float*)d_in[2];
  const float* b1  = (const float*)d_in[3];
  const float* W12 = (const float*)d_in[4];
  const float* b12 = (const float*)d_in[5];
  const float* W13 = (const float*)d_in[6];
  const float* b13 = (const float*)d_in[7];
  const float* W2  = (const float*)d_in[8];
  const float* b2  = (const float*)d_in[9];
  float* out = (float*)d_out;

  bf16* wp = (bf16*)d_ws;
  float* bp = (float*)((char*)d_ws + BP_OFF_BYTES);
  float* acc = (float*)((char*)d_ws + ACC_OFF_BYTES);

  hipMemsetAsync(acc, 0, ACC_FLOATS * sizeof(float), stream);
  pack_kernel<<<(WP_TOTAL + BP_FLOATS + 255) / 256, 256, 0, stream>>>(
      W1, b1, W12, b12, W13, b13, W2, b2, wp, bp);
  mlp_main<<<N_ROWS / 128, 256, 0, stream>>>(input, h, wp, bp, out, acc);
  finalize<<<1, 256, 0, stream>>>(acc, out);
}